// Round 1
// baseline (405.914 us; speedup 1.0000x reference)
//
#include <hip/hip_runtime.h>

#define LOG2E 1.442695040888963f

// One batch element per 64-thread block (one wave).
// Lane l owns gate rows l and l+64 (rows 0..103; gate order i,f,g,o).
// W_hh rows live in registers for the whole kernel; h is broadcast via LDS.
__launch_bounds__(64, 2)
__global__ void lstm_char_kernel(const int* __restrict__ x,      // [B,T] int32
                                 const float* __restrict__ E,     // [26,26]
                                 const float* __restrict__ W_ih,  // [104,26]
                                 const float* __restrict__ W_hh,  // [104,26]
                                 const float* __restrict__ b_ih,  // [104]
                                 const float* __restrict__ b_hh,  // [104]
                                 const float* __restrict__ W_lin, // [26,26]
                                 const float* __restrict__ b_lin, // [26]
                                 float* __restrict__ out,         // [B,26]
                                 int T)
{
    constexpr int H = 26;

    __shared__ float P[26][104];          // per-char fused input projection (+both biases)
    __shared__ float Ebuf[26 * 26];
    __shared__ int   chars[1024];
    __shared__ __align__(16) float hbuf[32];
    __shared__ float gbuf[104];

    const int b = blockIdx.x;
    const int l = threadIdx.x;
    const bool has1 = (l < 40);           // rows 64..103 exist only for l<40

    // ---- stage E and the char sequence into LDS ----
    for (int i = l; i < 26 * 26; i += 64) Ebuf[i] = E[i];
    for (int t = l; t < T; t += 64) chars[t] = x[(size_t)b * T + t];
    if (l < 32) hbuf[l] = 0.0f;
    __syncthreads();

    // ---- load my W_ih / W_hh rows into registers ----
    float wi0[H], wi1[H], wh0[H], wh1[H];
    #pragma unroll
    for (int k = 0; k < H; ++k) {
        wi0[k] = W_ih[l * H + k];
        wh0[k] = W_hh[l * H + k];
        wi1[k] = has1 ? W_ih[(64 + l) * H + k] : 0.0f;
        wh1[k] = has1 ? W_hh[(64 + l) * H + k] : 0.0f;
    }
    const float bias0 = b_ih[l] + b_hh[l];
    const float bias1 = has1 ? (b_ih[64 + l] + b_hh[64 + l]) : 0.0f;

    // ---- build P[ch][row] = E[ch]·W_ih[row] + b_ih[row] + b_hh[row] ----
    for (int ch = 0; ch < 26; ++ch) {
        float a0 = bias0, a1 = bias1;
        #pragma unroll
        for (int k = 0; k < H; ++k) {
            float e = Ebuf[ch * H + k];
            a0 = fmaf(wi0[k], e, a0);
            a1 = fmaf(wi1[k], e, a1);
        }
        P[ch][l] = a0;
        if (has1) P[ch][64 + l] = a1;
    }
    __syncthreads();

    // ---- per-lane activation constants (branchless sigmoid/tanh) ----
    // row r: i,f,o -> sigmoid; g (52..77) -> tanh
    // sigmoid(x) = rcp(1 + exp2(-x*log2e)); tanh(x) = 2*sigmoid(2x) - 1
    const bool t0 = (l >= 52);            // row l
    const bool t1 = (l < 14);             // row 64+l (64..77 = g)
    const float m0 = t0 ? -2.0f * LOG2E : -LOG2E;
    const float s0 = t0 ? 2.0f : 1.0f;
    const float d0 = t0 ? -1.0f : 0.0f;
    const float m1 = t1 ? -2.0f * LOG2E : -LOG2E;
    const float s1 = t1 ? 2.0f : 1.0f;
    const float d1 = t1 ? -1.0f : 0.0f;

    float c = 0.0f;                        // lanes 0..25 hold cell state c_l

    for (int t = 0; t < T; ++t) {
        const int ch = chars[t];

        float a0 = P[ch][l];
        float a1 = has1 ? P[ch][64 + l] : 0.0f;

        // broadcast h from LDS into registers (uniform-address b128 reads)
        float hr[28];
        #pragma unroll
        for (int q = 0; q < 7; ++q) {
            float4 v = *(((const float4*)hbuf) + q);
            hr[4 * q + 0] = v.x; hr[4 * q + 1] = v.y;
            hr[4 * q + 2] = v.z; hr[4 * q + 3] = v.w;
        }

        #pragma unroll
        for (int k = 0; k < H; ++k) {
            a0 = fmaf(wh0[k], hr[k], a0);
            a1 = fmaf(wh1[k], hr[k], a1);
        }

        // activations (branchless: per-lane constants)
        float y0 = __builtin_amdgcn_rcpf(1.0f + __builtin_amdgcn_exp2f(a0 * m0));
        y0 = fmaf(y0, s0, d0);
        float y1 = __builtin_amdgcn_rcpf(1.0f + __builtin_amdgcn_exp2f(a1 * m1));
        y1 = fmaf(y1, s1, d1);

        gbuf[l] = y0;
        if (has1) gbuf[64 + l] = y1;
        __syncthreads();

        if (l < H) {
            float gi = gbuf[l];
            float gf = gbuf[26 + l];
            float gg = gbuf[52 + l];
            float go = gbuf[78 + l];
            c = fmaf(gf, c, gi * gg);
            float th = fmaf(__builtin_amdgcn_rcpf(
                                1.0f + __builtin_amdgcn_exp2f(-2.0f * LOG2E * c)),
                            2.0f, -1.0f);
            hbuf[l] = go * th;
        }
        __syncthreads();
    }

    // ---- final linear: out[b, j] = W_lin[j]·h + b_lin[j] ----
    if (l < H) {
        float acc = b_lin[l];
        #pragma unroll
        for (int k = 0; k < H; ++k)
            acc = fmaf(W_lin[l * H + k], hbuf[k], acc);
        out[(size_t)b * H + l] = acc;
    }
}

extern "C" void kernel_launch(void* const* d_in, const int* in_sizes, int n_in,
                              void* d_out, int out_size, void* d_ws, size_t ws_size,
                              hipStream_t stream) {
    const int*   x     = (const int*)d_in[0];
    const float* E     = (const float*)d_in[1];
    const float* W_ih  = (const float*)d_in[2];
    const float* W_hh  = (const float*)d_in[3];
    const float* b_ih  = (const float*)d_in[4];
    const float* b_hh  = (const float*)d_in[5];
    const float* W_lin = (const float*)d_in[6];
    const float* b_lin = (const float*)d_in[7];
    float* out = (float*)d_out;

    const int T = 1024;
    const int B = in_sizes[0] / T;   // 2048

    lstm_char_kernel<<<B, 64, 0, stream>>>(x, E, W_ih, W_hh, b_ih, b_hh,
                                           W_lin, b_lin, out, T);
}

// Round 2
// 288.531 us; speedup vs baseline: 1.4068x; 1.4068x over previous
//
#include <hip/hip_runtime.h>

#define LOG2E 1.442695040888963f

// One batch element per 64-lane wave (one block).
// Row mapping (original torch gate order rows 0..103 = i,f,g,o):
//   lane l<52 owns row l (a0) and row l+52 (a1).
//   => l<26:      a0 = i_l (sigmoid), a1 = g_l (tanh)
//      l in[26,52): a0 = f_{l-26} (sigmoid), a1 = o_{l-26} (sigmoid)
// c/h update in lane l<26: f,o pulled from lane l+26 via ds_bpermute (no barrier).
// h broadcast through a 64-float LDS buffer; single-wave DS ordering makes the
// write->read visible without __syncthreads.
__launch_bounds__(64, 2)
__global__ void lstm_char_kernel(const int* __restrict__ x,      // [B,T] int32
                                 const float* __restrict__ E,     // [26,26]
                                 const float* __restrict__ W_ih,  // [104,26]
                                 const float* __restrict__ W_hh,  // [104,26]
                                 const float* __restrict__ b_ih,  // [104]
                                 const float* __restrict__ b_hh,  // [104]
                                 const float* __restrict__ W_lin, // [26,26]
                                 const float* __restrict__ b_lin, // [26]
                                 float* __restrict__ out,         // [B,26]
                                 int T)
{
    constexpr int H = 26;

    __shared__ float P[27][104];          // +1 row pad: lanes 52..63 over-read harmlessly
    __shared__ float Ebuf[26 * 26];
    __shared__ int   chars[1024 + 2];     // premultiplied byte offsets; +2 pad for prefetch
    __shared__ __align__(16) float hbuf[64];

    const int b = blockIdx.x;
    const int l = threadIdx.x;
    const bool act = (l < 52);
    const int r0 = act ? l : 0;           // clamped row indices for global loads
    const int r1 = act ? l + 52 : 0;

    // ---- stage E and the char sequence (as P-row byte offsets) ----
    for (int i = l; i < 26 * 26; i += 64) Ebuf[i] = E[i];
    for (int t = l; t < T; t += 64) chars[t] = x[(size_t)b * T + t] * (104 * 4);
    if (l < 2) chars[T + l] = 0;
    hbuf[l] = 0.0f;

    // ---- weights for my two rows into registers ----
    float wh0[H], wh1[H];
    {
        float wi0[H], wi1[H];
        #pragma unroll
        for (int k = 0; k < H; ++k) {
            wi0[k] = W_ih[r0 * H + k];
            wh0[k] = W_hh[r0 * H + k];
            wi1[k] = W_ih[r1 * H + k];
            wh1[k] = W_hh[r1 * H + k];
        }
        const float bias0 = b_ih[r0] + b_hh[r0];
        const float bias1 = b_ih[r1] + b_hh[r1];
        __syncthreads();

        // P[ch][row] = E[ch]·W_ih[row] + b_ih[row] + b_hh[row]
        for (int ch = 0; ch < 26; ++ch) {
            float a0 = bias0, a1 = bias1;
            #pragma unroll
            for (int k = 0; k < H; ++k) {
                float e = Ebuf[ch * H + k];
                a0 = fmaf(wi0[k], e, a0);
                a1 = fmaf(wi1[k], e, a1);
            }
            if (act) { P[ch][l] = a0; P[ch][52 + l] = a1; }
        }
    }
    __syncthreads();

    // ---- per-lane activation constants for a1 (tanh for l<26 [g], sigmoid else [o]) ----
    const float m1 = (l < 26) ? (-2.0f * LOG2E) : (-LOG2E);
    const float s1 = (l < 26) ? 2.0f : 1.0f;
    const float d1 = (l < 26) ? -1.0f : 0.0f;
    const int bpaddr = ((l + 26) & 63) << 2;   // ds_bpermute byte index of lane l+26

    // ---- software-pipeline prologue: P row for t=0 ready, offset for t=1 ready ----
    int poff0 = chars[0];
    int poffn = chars[1];
    const char* Pbase = (const char*)&P[0][0];
    const float* Pr0 = (const float*)(Pbase + poff0);
    float pa0 = Pr0[l];
    float pa1 = Pr0[l + 52];

    float c = 0.0f;

    #pragma unroll 2
    for (int t = 0; t < T; ++t) {
        // prefetch P row for t+1 and char offset for t+2 (off critical path)
        const float* Pn = (const float*)(Pbase + poffn);
        float pn0 = Pn[l];
        float pn1 = Pn[l + 52];
        int poff2 = chars[t + 2];

        // broadcast h (uniform-address b128 reads; ordered after prev ds_write)
        float hr[28];
        #pragma unroll
        for (int q = 0; q < 7; ++q) {
            float4 v = ((const float4*)hbuf)[q];
            hr[4 * q + 0] = v.x; hr[4 * q + 1] = v.y;
            hr[4 * q + 2] = v.z; hr[4 * q + 3] = v.w;
        }

        // gates: 4 independent FMA chains of 13
        float s00 = pa0, s01 = 0.0f, s10 = pa1, s11 = 0.0f;
        #pragma unroll
        for (int k = 0; k < H; k += 2) {
            s00 = fmaf(wh0[k],     hr[k],     s00);
            s01 = fmaf(wh0[k + 1], hr[k + 1], s01);
            s10 = fmaf(wh1[k],     hr[k],     s10);
            s11 = fmaf(wh1[k + 1], hr[k + 1], s11);
        }
        const float a0 = s00 + s01;
        const float a1 = s10 + s11;

        // activations: y0 = sigmoid(a0) for all lanes; y1 = tanh/sigmoid(a1)
        float y0 = __builtin_amdgcn_rcpf(1.0f + __builtin_amdgcn_exp2f(a0 * (-LOG2E)));
        float y1 = fmaf(__builtin_amdgcn_rcpf(1.0f + __builtin_amdgcn_exp2f(a1 * m1)),
                        s1, d1);

        // pull f,o from lane l+26 (valid for l<26; garbage elsewhere, unused)
        float fg = __int_as_float(__builtin_amdgcn_ds_bpermute(bpaddr, __float_as_int(y0)));
        float og = __int_as_float(__builtin_amdgcn_ds_bpermute(bpaddr, __float_as_int(y1)));

        // c, h update (meaningful in lanes 0..25; harmless garbage elsewhere)
        c = fmaf(fg, c, y0 * y1);
        float th = fmaf(__builtin_amdgcn_rcpf(
                            1.0f + __builtin_amdgcn_exp2f(c * (-2.0f * LOG2E))),
                        2.0f, -1.0f);
        hbuf[l] = og * th;

        pa0 = pn0; pa1 = pn1; poffn = poff2;
    }

    __syncthreads();

    // ---- final linear: out[b, j] = W_lin[j]·h + b_lin[j] ----
    if (l < H) {
        float acc = b_lin[l];
        #pragma unroll
        for (int k = 0; k < H; ++k)
            acc = fmaf(W_lin[l * H + k], hbuf[k], acc);
        out[(size_t)b * H + l] = acc;
    }
}

extern "C" void kernel_launch(void* const* d_in, const int* in_sizes, int n_in,
                              void* d_out, int out_size, void* d_ws, size_t ws_size,
                              hipStream_t stream) {
    const int*   x     = (const int*)d_in[0];
    const float* E     = (const float*)d_in[1];
    const float* W_ih  = (const float*)d_in[2];
    const float* W_hh  = (const float*)d_in[3];
    const float* b_ih  = (const float*)d_in[4];
    const float* b_hh  = (const float*)d_in[5];
    const float* W_lin = (const float*)d_in[6];
    const float* b_lin = (const float*)d_in[7];
    float* out = (float*)d_out;

    const int T = 1024;
    const int B = in_sizes[0] / T;   // 2048

    lstm_char_kernel<<<B, 64, 0, stream>>>(x, E, W_ih, W_hh, b_ih, b_hh,
                                           W_lin, b_lin, out, T);
}